// Round 18
// baseline (250.930 us; speedup 1.0000x reference)
//
#include <hip/hip_runtime.h>

#define NN 50000
#define NE 400000
#define NH 4
#define NTY 3
#define ETY 4
#define EDIM 32
#define NBLK 196   // ceil(NN/256)
#define BM 32      // gemm rows per block
#define GGRID ((NN + BM - 1) / BM + NTY)   // flat gemm grid upper bound

typedef __attribute__((ext_vector_type(8))) short bf16x8;
typedef __attribute__((ext_vector_type(4))) float f32x4;

static __device__ __forceinline__ unsigned short f2bf(float f) {
    unsigned u = __float_as_uint(f);
    unsigned r = (u + 0x7FFFu + ((u >> 16) & 1u)) >> 16;   // RNE
    return (unsigned short)r;
}
static __device__ __forceinline__ float bf2f(unsigned short s) {
    return __uint_as_float(((unsigned)s) << 16);
}

// ---------------------------------------------------------------- prep: fold u(->Uf frag layout), v
__global__ __launch_bounds__(256) void prep_fold(
    const float* __restrict__ W_dst1, const float* __restrict__ att_dst1,
    const float* __restrict__ W_edge1, const float* __restrict__ att_edge1,
    const float* __restrict__ W_dst2, const float* __restrict__ att_dst2,
    const float* __restrict__ W_edge2, const float* __restrict__ att_edge2,
    ushort* __restrict__ uf1, ushort* __restrict__ uf2,
    float* __restrict__ v1, float* __restrict__ v2)
{
    int idx = blockIdx.x * 256 + threadIdx.x;   // 25600 total
    if (idx < 24576) {
        const float* W; const float* A; ushort* U; int i;
        if (idx < 12288) { W = W_dst1; A = att_dst1; U = uf1; i = idx; }
        else             { W = W_dst2; A = att_dst2; U = uf2; i = idx - 12288; }
        int d = i & 255, h = (i >> 8) & 3, t = (i >> 10) & 3, tn = i >> 12;
        const float* wp = W + tn * 65536 + d * 256 + h * 64;
        const float* ap = A + t * 256 + h * 64;
        float s = 0.f;
        #pragma unroll 8
        for (int c = 0; c < 64; ++c) s += wp[c] * ap[c];
        int th = t * 4 + h;
        int ks = d >> 5, g = (d >> 3) & 3, e = d & 7;
        U[(size_t)tn * 4096 + ks * 512 + (g * 16 + th) * 8 + e] = f2bf(s);
    } else {
        int i = idx - 24576;
        const float* W; const float* A; float* V;
        if (i < 512) { W = W_edge1; A = att_edge1; V = v1; }
        else         { W = W_edge2; A = att_edge2; V = v2; i -= 512; }
        int d = i & 31, h = (i >> 5) & 3, t = i >> 7;
        const float* wp = W + t * (EDIM * 256) + d * 256 + h * 64;
        const float* ap = A + t * 256 + h * 64;
        float s = 0.f;
        #pragma unroll 8
        for (int c = 0; c < 64; ++c) s += wp[c] * ap[c];
        V[(t * 4 + h) * 32 + d] = s;
    }
}

// ---------------------------------------------------------------- prep: Wf fragment layout
__global__ __launch_bounds__(256) void prep_wt(
    const float* __restrict__ W1, const float* __restrict__ W2,
    ushort* __restrict__ Wf1, ushort* __restrict__ Wf2)
{
    int idx = blockIdx.x * 256 + threadIdx.x;   // 393216 total
    const int HALF = 196608;
    const float* W = (idx < HALF) ? W1 : W2;
    ushort* O = (idx < HALF) ? Wf1 : Wf2;
    int i = (idx < HALF) ? idx : idx - HALF;
    int n = i & 255, k = (i >> 8) & 255, t = i >> 16;
    int c16 = n >> 4, r16 = n & 15;
    int ks = k >> 5, g = (k >> 3) & 3, e = k & 7;
    O[(size_t)t * 65536 + (c16 * 8 + ks) * 512 + (g * 16 + r16) * 8 + e] =
        f2bf(W[(size_t)t * 65536 + k * 256 + n]);
}

// ---------------------------------------------------------------- CSR build
__global__ void hist_k(const int* __restrict__ dst, int* __restrict__ cnt)
{
    int i = blockIdx.x * 256 + threadIdx.x;
    if (i < NE) atomicAdd(&cnt[dst[i]], 1);
}

__global__ __launch_bounds__(256) void csr_blocksum(
    const int* __restrict__ cnt, const int* __restrict__ ntype,
    int* __restrict__ blks)  // [4][NBLK]
{
    int tid = threadIdx.x, b = blockIdx.x;
    int j = b * 256 + tid;
    int c = (j < NN) ? cnt[j] : 0;
    int t = (j < NN) ? ntype[j] : 3;
    int p = (t < 3) ? (1 << (t * 10)) : 0;
    #pragma unroll
    for (int d = 1; d < 64; d <<= 1) { c += __shfl_xor(c, d); p += __shfl_xor(p, d); }
    __shared__ int ws[2][4];
    int lane = tid & 63, w = tid >> 6;
    if (lane == 0) { ws[0][w] = c; ws[1][w] = p; }
    __syncthreads();
    if (tid == 0) {
        int C = ws[0][0] + ws[0][1] + ws[0][2] + ws[0][3];
        int P = ws[1][0] + ws[1][1] + ws[1][2] + ws[1][3];
        blks[b]            = C;
        blks[NBLK + b]     = P & 1023;
        blks[2 * NBLK + b] = (P >> 10) & 1023;
        blks[3 * NBLK + b] = (P >> 20) & 1023;
    }
}

__global__ __launch_bounds__(256) void csr_scanmid(int* __restrict__ blks,
                                                   int* __restrict__ ntoff,
                                                   int* __restrict__ gblk)
{
    __shared__ int4 part[256];
    int tid = threadIdx.x;
    int4 v = make_int4(0, 0, 0, 0);
    if (tid < NBLK)
        v = make_int4(blks[tid], blks[NBLK + tid], blks[2 * NBLK + tid], blks[3 * NBLK + tid]);
    int4 orig = v;
    part[tid] = v;
    __syncthreads();
    for (int off = 1; off < 256; off <<= 1) {
        int4 u = (tid >= off) ? part[tid - off] : make_int4(0, 0, 0, 0);
        __syncthreads();
        part[tid].x += u.x; part[tid].y += u.y; part[tid].z += u.z; part[tid].w += u.w;
        __syncthreads();
    }
    int4 inc = part[tid];
    if (tid < NBLK) {
        blks[tid]            = inc.x - orig.x;
        blks[NBLK + tid]     = inc.y - orig.y;
        blks[2 * NBLK + tid] = inc.z - orig.z;
        blks[3 * NBLK + tid] = inc.w - orig.w;
    }
    if (tid == 255) {
        ntoff[0] = 0; ntoff[1] = inc.y; ntoff[2] = inc.y + inc.z;
        ntoff[3] = inc.y + inc.z + inc.w;
        int b0 = (inc.y + BM - 1) / BM;
        int b1 = (inc.z + BM - 1) / BM;
        int b2 = (inc.w + BM - 1) / BM;
        gblk[0] = 0; gblk[1] = b0; gblk[2] = b0 + b1; gblk[3] = b0 + b1 + b2;
    }
}

// Also emits inv_perm (original node -> permuted position).
__global__ __launch_bounds__(256) void csr_apply(
    const int* __restrict__ cnt, const int* __restrict__ ntype,
    const int* __restrict__ blks, const int* __restrict__ ntoff,
    int* __restrict__ row_ptr, int* __restrict__ node_perm,
    int* __restrict__ inv_perm)
{
    int tid = threadIdx.x, b = blockIdx.x;
    int j = b * 256 + tid;
    int c = (j < NN) ? cnt[j] : 0;
    int t = (j < NN) ? ntype[j] : 3;
    int p = (t < 3) ? (1 << (t * 10)) : 0;
    int lane = tid & 63, w = tid >> 6;
    int ic = c, ip = p;
    #pragma unroll
    for (int d = 1; d < 64; d <<= 1) {
        int uc = __shfl_up(ic, d), up = __shfl_up(ip, d);
        if (lane >= d) { ic += uc; ip += up; }
    }
    __shared__ int ws[2][4];
    if (lane == 63) { ws[0][w] = ic; ws[1][w] = ip; }
    __syncthreads();
    int coff = 0, poff = 0;
    for (int i = 0; i < w; ++i) { coff += ws[0][i]; poff += ws[1][i]; }
    int exc  = ic - c + coff;
    int expp = ip - p + poff;
    if (j < NN) {
        row_ptr[j] = blks[b] + exc;
        if (t < 3) {
            int tb   = blks[(t + 1) * NBLK + b];
            int tpfx = (expp >> (t * 10)) & 1023;
            int pos  = ntoff[t] + tb + tpfx;
            node_perm[pos] = j;
            inv_perm[j] = pos;
        }
    }
    if (j == 0) row_ptr[NN] = NE;
}

// Light scatter: CSR slot + packed (permuted src)|etype + edge->slot map.
__global__ void scatter_k(const int* __restrict__ src, const int* __restrict__ dst,
                          const int* __restrict__ etype, const int* __restrict__ inv,
                          const int* __restrict__ row_ptr, int* __restrict__ cursor,
                          int* __restrict__ spk, int* __restrict__ e2c)
{
    int i = blockIdx.x * 256 + threadIdx.x;
    if (i >= NE) return;
    int d = dst[i];
    int pos = row_ptr[d] + atomicAdd(&cursor[d], 1);
    spk[pos] = inv[src[i]] | (etype[i] << 16);
    e2c[i] = pos;
}

// Edge scores, edge order: eattr + e2c coalesced, v tables in LDS,
// results scatter-stored to CSR slots.
__global__ __launch_bounds__(256) void sedge_k(
    const float* __restrict__ eattr, const int* __restrict__ etype,
    const int* __restrict__ e2c,
    const float* __restrict__ v1, const float* __restrict__ v2,
    float* __restrict__ sedge1c, float* __restrict__ sedge2c)
{
    __shared__ float v1l[512], v2l[512];
    int tid = threadIdx.x;
    v1l[tid] = v1[tid]; v1l[tid + 256] = v1[tid + 256];
    v2l[tid] = v2[tid]; v2l[tid + 256] = v2[tid + 256];
    __syncthreads();

    int i = blockIdx.x * 256 + tid;
    if (i >= NE) return;
    int t = etype[i];
    int pos = e2c[i];
    float4 ea[8];
    #pragma unroll
    for (int q = 0; q < 8; ++q) ea[q] = *(const float4*)(eattr + (size_t)i * 32 + q * 4);
    float4 o1, o2;
    #pragma unroll
    for (int h = 0; h < 4; ++h) {
        const float* vp1 = v1l + (t * 4 + h) * 32;
        const float* vp2 = v2l + (t * 4 + h) * 32;
        float s1 = 0.f, s2 = 0.f;
        #pragma unroll
        for (int q = 0; q < 8; ++q) {
            float4 w1 = *(const float4*)(vp1 + q * 4);
            float4 w2 = *(const float4*)(vp2 + q * 4);
            s1 += ea[q].x * w1.x + ea[q].y * w1.y + ea[q].z * w1.z + ea[q].w * w1.w;
            s2 += ea[q].x * w2.x + ea[q].y * w2.y + ea[q].z * w2.z + ea[q].w * w2.w;
        }
        ((float*)&o1)[h] = s1;
        ((float*)&o2)[h] = s2;
    }
    *(float4*)(sedge1c + (size_t)pos * 4) = o1;
    *(float4*)(sedge2c + (size_t)pos * 4) = o2;
}

// ---------------------------------------------------------------- fused GEMM + s_dst + s_src (+convert)
// R16 structure: 1-deep register double-buffer for W/U (known-good 47us).
__global__ __launch_bounds__(256) void gemm3_k(
    const ushort* __restrict__ xb, const float* __restrict__ xf,
    const ushort* __restrict__ Wf, const ushort* __restrict__ Uf,
    const float* __restrict__ att_src,
    const int* __restrict__ node_perm, const int* __restrict__ ntoff,
    const int* __restrict__ gblk,
    ushort* __restrict__ xout, float* __restrict__ s_dst,
    float* __restrict__ s_src)
{
    int b = blockIdx.x;
    if (b >= gblk[3]) return;
    int t = (b >= gblk[1]) + (b >= gblk[2]);
    int row0 = ntoff[t] + (b - gblk[t]) * BM;
    int seg1 = ntoff[t + 1];

    __shared__ __align__(16) ushort Xl[BM * 256];  // 16 KB

    int tid = threadIdx.x;
    int w = tid >> 6, l = tid & 63;
    int kb = (tid & 31) * 16;               // bf16 byte offset in a 512B row

    #pragma unroll
    for (int it = 0; it < 4; ++it) {
        int row = it * 8 + (tid >> 5);      // 8 rows per iteration
        int rp = row0 + row;
        int rr = (rp < seg1) ? rp : seg1 - 1;
        uint4 pv;
        if (xf) {
            int gr = node_perm[rr];
            const char* src = (const char*)(xf + (size_t)gr * 256) + kb * 2;
            float4 f0 = *(const float4*)(src);
            float4 f1 = *(const float4*)(src + 16);
            pv.x = (unsigned)f2bf(f0.x) | ((unsigned)f2bf(f0.y) << 16);
            pv.y = (unsigned)f2bf(f0.z) | ((unsigned)f2bf(f0.w) << 16);
            pv.z = (unsigned)f2bf(f1.x) | ((unsigned)f2bf(f1.y) << 16);
            pv.w = (unsigned)f2bf(f1.z) | ((unsigned)f2bf(f1.w) << 16);
        } else {
            pv = *(const uint4*)((const char*)(xb + (size_t)rr * 256) + kb);
        }
        *(uint4*)((char*)Xl + row * 512 + (kb ^ ((row & 7) << 4))) = pv;
    }
    __syncthreads();

    int g = l >> 4, r16 = l & 15;
    const ushort* wfb = Wf + (size_t)(t * 16 + w * 4) * 8 * 512;  // this wave's 4 c16-tiles
    const ushort* ufb = Uf + (size_t)t * 4096;

    f32x4 acc[2][4];                         // [fr (x-row group)][cf (col group)]
    #pragma unroll
    for (int i = 0; i < 2; ++i)
        #pragma unroll
        for (int j = 0; j < 4; ++j) acc[i][j] = (f32x4){0.f, 0.f, 0.f, 0.f};
    f32x4 uacc[2] = {{0.f,0.f,0.f,0.f},{0.f,0.f,0.f,0.f}};

    // register double-buffer for W/U fragments
    bf16x8 aW[4], aU, nW[4], nU;
    #pragma unroll
    for (int cf = 0; cf < 4; ++cf)
        aW[cf] = *(const bf16x8*)(wfb + (cf * 8 + 0) * 512 + l * 8);
    aU = *(const bf16x8*)(ufb + 0 * 512 + l * 8);

    #pragma unroll
    for (int ks = 0; ks < 8; ++ks) {
        if (ks < 7) {
            #pragma unroll
            for (int cf = 0; cf < 4; ++cf)
                nW[cf] = *(const bf16x8*)(wfb + (cf * 8 + ks + 1) * 512 + l * 8);
            nU = *(const bf16x8*)(ufb + (ks + 1) * 512 + l * 8);
        }
        int kbyte = ks * 64 + g * 16;
        bf16x8 b0 = *(const bf16x8*)((const char*)Xl + r16 * 512 + (kbyte ^ ((r16 & 7) << 4)));
        bf16x8 b1 = *(const bf16x8*)((const char*)Xl + (16 + r16) * 512 + (kbyte ^ (((16 + r16) & 7) << 4)));
        #pragma unroll
        for (int cf = 0; cf < 4; ++cf) {
            acc[0][cf] = __builtin_amdgcn_mfma_f32_16x16x32_bf16(aW[cf], b0, acc[0][cf], 0, 0, 0);
            acc[1][cf] = __builtin_amdgcn_mfma_f32_16x16x32_bf16(aW[cf], b1, acc[1][cf], 0, 0, 0);
        }
        uacc[0] = __builtin_amdgcn_mfma_f32_16x16x32_bf16(aU, b0, uacc[0], 0, 0, 0);
        uacc[1] = __builtin_amdgcn_mfma_f32_16x16x32_bf16(aU, b1, uacc[1], 0, 0, 0);
        if (ks < 7) {
            #pragma unroll
            for (int cf = 0; cf < 4; ++cf) aW[cf] = nW[cf];
            aU = nU;
        }
    }

    // s_src epilogue: head w, s_src[rp, te*4+w] = sum_c acc(row, c) * att_src[te][w][c]
    float p[4][2];
    #pragma unroll
    for (int te = 0; te < 4; ++te) { p[te][0] = 0.f; p[te][1] = 0.f; }
    #pragma unroll
    for (int te = 0; te < 4; ++te) {
        #pragma unroll
        for (int cf = 0; cf < 4; ++cf) {
            float4 av = *(const float4*)(att_src + te * 256 + w * 64 + cf * 16 + g * 4);
            #pragma unroll
            for (int fr = 0; fr < 2; ++fr) {
                p[te][fr] += acc[fr][cf][0] * av.x + acc[fr][cf][1] * av.y
                           + acc[fr][cf][2] * av.z + acc[fr][cf][3] * av.w;
            }
        }
    }
    #pragma unroll
    for (int te = 0; te < 4; ++te)
        #pragma unroll
        for (int fr = 0; fr < 2; ++fr) {
            p[te][fr] += __shfl_xor(p[te][fr], 16);
            p[te][fr] += __shfl_xor(p[te][fr], 32);
        }

    int col0 = w * 64;
    #pragma unroll
    for (int fr = 0; fr < 2; ++fr) {
        int rp = row0 + fr * 16 + r16;       // D col = lane&15 -> X row
        if (rp < seg1) {
            ushort* orow = xout + (size_t)rp * 256;
            #pragma unroll
            for (int cf = 0; cf < 4; ++cf) {
                ushort4 o;
                o.x = f2bf(acc[fr][cf][0]); o.y = f2bf(acc[fr][cf][1]);
                o.z = f2bf(acc[fr][cf][2]); o.w = f2bf(acc[fr][cf][3]);
                *(ushort4*)(orow + col0 + cf * 16 + g * 4) = o;   // D row m -> channel
            }
            if (w == 0) {
                int gr = node_perm[rp];
                *(float4*)(s_dst + (size_t)gr * 16 + g * 4) =
                    make_float4(uacc[fr][0], uacc[fr][1], uacc[fr][2], uacc[fr][3]);
            }
            if (g == 0) {
                #pragma unroll
                for (int te = 0; te < 4; ++te)
                    s_src[(size_t)rp * 16 + te * 4 + w] = p[te][fr];
            }
        }
    }
}

// ---------------------------------------------------------------- fused attention
static __device__ __forceinline__ float4 alpha_slot(
    int k, int n, const int* __restrict__ spk, const float* __restrict__ s_src,
    const float* __restrict__ s_dst, const float* __restrict__ sedgec, int* sOut)
{
    int pk = spk[k];
    int s = pk & 0xFFFF;      // permuted src position
    int t = pk >> 16;
    float4 ss = *(const float4*)(s_src + (size_t)s * 16 + t * 4);
    float4 sd = *(const float4*)(s_dst + (size_t)n * 16 + t * 4);
    float4 se = *(const float4*)(sedgec + (size_t)k * 4);
    float4 a;
    a.x = ss.x + sd.x + se.x; a.x = (a.x >= 0.f) ? a.x : 0.2f * a.x;
    a.y = ss.y + sd.y + se.y; a.y = (a.y >= 0.f) ? a.y : 0.2f * a.y;
    a.z = ss.z + sd.z + se.z; a.z = (a.z >= 0.f) ? a.z : 0.2f * a.z;
    a.w = ss.w + sd.w + se.w; a.w = (a.w >= 0.f) ? a.w : 0.2f * a.w;
    *sOut = s;
    return a;
}

// Block = 16 nodes. Phase A: 16-lane group per node; slot tables zero-filled to
// 64. Phase B: TWO nodes interleaved per pass (2x independent gather streams,
// 16 loads in flight). Mode-1 output to PERMUTED position inv[n].
__global__ __launch_bounds__(256) void attn_k(
    const ushort* __restrict__ xsb, const float* __restrict__ s_src,
    const float* __restrict__ s_dst, const float* __restrict__ sedgec,
    const int* __restrict__ row_ptr, const int* __restrict__ spk,
    const int* __restrict__ inv,
    const float* __restrict__ bias, const float* __restrict__ gamma,
    const float* __restrict__ beta, void* __restrict__ out, int mode)
{
    __shared__ float  wlds[16][256];   // 16 KB
    __shared__ int    slds[16][64];    //  4 KB
    __shared__ float4 mxl[16], invl[16];

    int w = threadIdx.x >> 6;
    int lane = threadIdx.x & 63;
    int j = lane >> 4, li = lane & 15;
    int nid = w * 4 + j;
    int n = blockIdx.x * 16 + nid;
    int beg = row_ptr[n], end = row_ptr[n + 1];
    int deg = end - beg;

    // ---- phase A: weights (16 lanes per node)
    int k0 = beg + li;
    bool act = li < deg;
    int sF = 0;
    float4 aF = make_float4(-1e30f, -1e30f, -1e30f, -1e30f);
    if (act) aF = alpha_slot(k0, n, spk, s_src, s_dst, sedgec, &sF);

    float4 mx = aF;
    for (int k = k0 + 16; k < end; k += 16) {   // deg > 16: ~0.3% of nodes
        int s2; float4 t = alpha_slot(k, n, spk, s_src, s_dst, sedgec, &s2);
        mx.x = fmaxf(mx.x, t.x); mx.y = fmaxf(mx.y, t.y);
        mx.z = fmaxf(mx.z, t.z); mx.w = fmaxf(mx.w, t.w);
    }
    #pragma unroll
    for (int d = 1; d < 16; d <<= 1) {
        mx.x = fmaxf(mx.x, __shfl_xor(mx.x, d, 16));
        mx.y = fmaxf(mx.y, __shfl_xor(mx.y, d, 16));
        mx.z = fmaxf(mx.z, __shfl_xor(mx.z, d, 16));
        mx.w = fmaxf(mx.w, __shfl_xor(mx.w, d, 16));
    }
    float4 ex = make_float4(0.f, 0.f, 0.f, 0.f);
    if (act) {
        ex.x = __expf(aF.x - mx.x); ex.y = __expf(aF.y - mx.y);
        ex.z = __expf(aF.z - mx.z); ex.w = __expf(aF.w - mx.w);
    }
    float4 sm = ex;
    for (int k = k0 + 16; k < end; k += 16) {
        int s2; float4 t = alpha_slot(k, n, spk, s_src, s_dst, sedgec, &s2);
        sm.x += __expf(t.x - mx.x); sm.y += __expf(t.y - mx.y);
        sm.z += __expf(t.z - mx.z); sm.w += __expf(t.w - mx.w);
    }
    #pragma unroll
    for (int d = 1; d < 16; d <<= 1) {
        sm.x += __shfl_xor(sm.x, d, 16); sm.y += __shfl_xor(sm.y, d, 16);
        sm.z += __shfl_xor(sm.z, d, 16); sm.w += __shfl_xor(sm.w, d, 16);
    }
    float4 inv4;
    inv4.x = 1.f / (sm.x + 1e-16f); inv4.y = 1.f / (sm.y + 1e-16f);
    inv4.z = 1.f / (sm.z + 1e-16f); inv4.w = 1.f / (sm.w + 1e-16f);

    if (act) {
        *(float4*)&wlds[nid][li * 4] = make_float4(ex.x * inv4.x, ex.y * inv4.y,
                                                   ex.z * inv4.z, ex.w * inv4.w);
        slds[nid][li] = sF;
    }
    for (int k = k0 + 16; k < end && (k - beg) < 64; k += 16) {  // slots 16..63
        int s2; float4 t = alpha_slot(k, n, spk, s_src, s_dst, sedgec, &s2);
        int slot = k - beg;
        *(float4*)&wlds[nid][slot * 4] = make_float4(
            __expf(t.x - mx.x) * inv4.x, __expf(t.y - mx.y) * inv4.y,
            __expf(t.z - mx.z) * inv4.z, __expf(t.w - mx.w) * inv4.w);
        slds[nid][slot] = s2;
    }
    // zero-fill slots deg..63: zero weight * row 0 contributes exactly nothing
    {
        int nf = (deg < 64) ? deg : 64;
        for (int slot = li; slot < 64; slot += 16) {
            if (slot >= nf) {
                *(float4*)&wlds[nid][slot * 4] = make_float4(0.f, 0.f, 0.f, 0.f);
                slds[nid][slot] = 0;
            }
        }
    }
    if (li == 0) { mxl[nid] = mx; invl[nid] = inv4; }

    // ---- phase B: wave processes its 4 nodes, 2 at a time (2x MLP)
    int h2 = lane >> 4;
    for (int jp = 0; jp < 2; ++jp) {
        int nbA = w * 4 + jp * 2;
        int nbB = nbA + 1;
        int begA = __shfl(beg, (jp * 2) * 16);
        int degA = __shfl(deg, (jp * 2) * 16);
        int begB = __shfl(beg, (jp * 2 + 1) * 16);
        int degB = __shfl(deg, (jp * 2 + 1) * 16);

        float4 accA = make_float4(0.f, 0.f, 0.f, 0.f);
        float4 accB = make_float4(0.f, 0.f, 0.f, 0.f);
        int nfA = (degA < 64) ? degA : 64;
        int nfB = (degB < 64) ? degB : 64;
        int nfM = (nfA > nfB) ? nfA : nfB;
        int nR = (nfM + 7) & ~7;
        for (int i = 0; i < nR; i += 8) {
            #pragma unroll
            for (int u = 0; u < 8; ++u) {
                float wvA = wlds[nbA][(i + u) * 4 + h2];
                int sA = slds[nbA][i + u];
                float wvB = wlds[nbB][(i + u) * 4 + h2];
                int sB = slds[nbB][i + u];
                ushort4 xa = *(const ushort4*)(xsb + (size_t)sA * 256 + lane * 4);
                ushort4 xc = *(const ushort4*)(xsb + (size_t)sB * 256 + lane * 4);
                accA.x += wvA * bf2f(xa.x); accA.y += wvA * bf2f(xa.y);
                accA.z += wvA * bf2f(xa.z); accA.w += wvA * bf2f(xa.w);
                accB.x += wvB * bf2f(xc.x); accB.y += wvB * bf2f(xc.y);
                accB.z += wvB * bf2f(xc.z); accB.w += wvB * bf2f(xc.w);
            }
        }
        // rare slow path (deg > 64)
        #pragma unroll
        for (int which = 0; which < 2; ++which) {
            int nb = which ? nbB : nbA;
            int begj = which ? begB : begA;
            int degj = which ? degB : degA;
            if (degj > 64) {
                int nn = blockIdx.x * 16 + nb;
                float4 mxj = mxl[nb], invj = invl[nb];
                float mxh  = (h2 == 0) ? mxj.x  : (h2 == 1) ? mxj.y  : (h2 == 2) ? mxj.z  : mxj.w;
                float invh = (h2 == 0) ? invj.x : (h2 == 1) ? invj.y : (h2 == 2) ? invj.z : invj.w;
                for (int k = begj + 64; k < begj + degj; ++k) {
                    int pk = spk[k];
                    int s = pk & 0xFFFF, t = pk >> 16;
                    float a = s_src[(size_t)s * 16 + t * 4 + h2]
                            + s_dst[(size_t)nn * 16 + t * 4 + h2]
                            + sedgec[(size_t)k * 4 + h2];
                    a = (a >= 0.f) ? a : 0.2f * a;
                    float wv = __expf(a - mxh) * invh;
                    ushort4 xv = *(const ushort4*)(xsb + (size_t)s * 256 + lane * 4);
                    float4& acc = which ? accB : accA;
                    acc.x += wv * bf2f(xv.x);
                    acc.y += wv * bf2f(xv.y);
                    acc.z += wv * bf2f(xv.z);
                    acc.w += wv * bf2f(xv.w);
                }
            }
        }

        // epilogue for the two nodes
        #pragma unroll
        for (int which = 0; which < 2; ++which) {
            float4 acc = which ? accB : accA;
            int nn = blockIdx.x * 16 + (which ? nbB : nbA);
            if (mode == 1) {
                float4 bb = *(const float4*)(bias + lane * 4);
                float vals[4] = { acc.x + bb.x, acc.y + bb.y, acc.z + bb.z, acc.w + bb.w };
                float s = vals[0] + vals[1] + vals[2] + vals[3];
                s += __shfl_xor(s, 1); s += __shfl_xor(s, 2); s += __shfl_xor(s, 4);
                s += __shfl_xor(s, 8); s += __shfl_xor(s, 16); s += __shfl_xor(s, 32);
                float mu = s * (1.f / 256.f);
                float q = 0.f;
                #pragma unroll
                for (int jq = 0; jq < 4; ++jq) { float d = vals[jq] - mu; q += d * d; }
                q += __shfl_xor(q, 1); q += __shfl_xor(q, 2); q += __shfl_xor(q, 4);
                q += __shfl_xor(q, 8); q += __shfl_xor(q, 16); q += __shfl_xor(q, 32);
                float r = rsqrtf(q * (1.f / 256.f) + 1e-5f);
                float4 gg = *(const float4*)(gamma + lane * 4);
                float4 be = *(const float4*)(beta + lane * 4);
                ushort4 o; float y;
                y = (vals[0] - mu) * r * gg.x + be.x; o.x = f2bf((y > 0.f) ? y : (__expf(y) - 1.f));
                y = (vals[1] - mu) * r * gg.y + be.y; o.y = f2bf((y > 0.f) ? y : (__expf(y) - 1.f));
                y = (vals[2] - mu) * r * gg.z + be.z; o.z = f2bf((y > 0.f) ? y : (__expf(y) - 1.f));
                y = (vals[3] - mu) * r * gg.w + be.w; o.w = f2bf((y > 0.f) ? y : (__expf(y) - 1.f));
                int npos = inv[nn];
                *(ushort4*)((ushort*)out + (size_t)npos * 256 + lane * 4) = o;
            } else {
                float4 am = acc;
                am.x += __shfl_xor(am.x, 16); am.x += __shfl_xor(am.x, 32);
                am.y += __shfl_xor(am.y, 16); am.y += __shfl_xor(am.y, 32);
                am.z += __shfl_xor(am.z, 16); am.z += __shfl_xor(am.z, 32);
                am.w += __shfl_xor(am.w, 16); am.w += __shfl_xor(am.w, 32);
                if (lane < 16) {
                    float4 bb = *(const float4*)(bias + lane * 4);
                    float4 o;
                    o.x = am.x * 0.25f + bb.x;
                    o.y = am.y * 0.25f + bb.y;
                    o.z = am.z * 0.25f + bb.z;
                    o.w = am.w * 0.25f + bb.w;
                    *(float4*)((float*)out + (size_t)nn * 64 + lane * 4) = o;
                }
            }
        }
    }
}

// ---------------------------------------------------------------- launch
extern "C" void kernel_launch(void* const* d_in, const int* in_sizes, int n_in,
                              void* d_out, int out_size, void* d_ws, size_t ws_size,
                              hipStream_t stream)
{
    (void)in_sizes; (void)n_in; (void)out_size;
    const float* x        = (const float*)d_in[0];
    const int*   ei       = (const int*)d_in[1];
    const int*   ntype    = (const int*)d_in[2];
    const int*   etype    = (const int*)d_in[3];
    const float* eattr    = (const float*)d_in[4];
    const float* W_src1   = (const float*)d_in[5];
    const float* W_dst1   = (const float*)d_in[6];
    const float* att_src1 = (const float*)d_in[7];
    const float* att_dst1 = (const float*)d_in[8];
    const float* W_edge1  = (const float*)d_in[9];
    const float* att_edge1= (const float*)d_in[10];
    const float* bias1    = (const float*)d_in[11];
    const float* gamma1   = (const float*)d_in[12];
    const float* beta1    = (const float*)d_in[13];
    const float* W_src2   = (const float*)d_in[14];
    const float* W_dst2   = (const float*)d_in[15];
    const float* att_src2 = (const float*)d_in[16];
    const float* att_dst2 = (const float*)d_in[17];
    const float* W_edge2  = (const float*)d_in[18];
    const float* att_edge2= (const float*)d_in[19];
    const float* bias2    = (const float*)d_in[20];

    char* w = (char*)d_ws;
    size_t off = 0;
    auto carve = [&](size_t bytes) -> char* {
        char* p = w + off;
        off = (off + bytes + 255) & ~(size_t)255;
        return p;
    };
    ushort* x_srcb  = (ushort*)carve((size_t)NN * 256 * 2);   // bf16 x_src (permuted)
    ushort* hb      = (ushort*)carve((size_t)NN * 256 * 2);   // bf16 h (permuted)
    float* s_src    = (float*)carve((size_t)NN * 16 * 4);     // permuted
    float* s_dst    = (float*)carve((size_t)NN * 16 * 4);     // original
    float* sedge1c  = (float*)carve((size_t)NE * 4 * 4);
    float* sedge2c  = (float*)carve((size_t)NE * 4 * 4);
    int*   cnt      = (int*)carve((size_t)(2 * NN) * 4);
    int*   cursor   = cnt + NN;
    int*   row_ptr  = (int*)carve((size_t)(NN + 1) * 4);
    int*   spk      = (int*)carve((size_t)NE * 4);
    int*   e2c      = (int*)carve((size_t)NE * 4);
    int*   node_perm= (int*)carve((size_t)NN * 4);
    int*   inv_perm = (int*)carve((size_t)NN * 4);
    int*   ntoff    = (int*)carve(4 * 4);
    int*   gblk     = (int*)carve(4 * 4);
    int*   blks     = (int*)carve((size_t)(4 * NBLK) * 4);
    ushort* uf1     = (ushort*)carve(12288 * 2);
    ushort* uf2     = (ushort*)carve(12288 * 2);
    float* v1       = (float*)carve(512 * 4);
    float* v2       = (float*)carve(512 * 4);
    ushort* Wf1     = (ushort*)carve((size_t)196608 * 2);
    ushort* Wf2     = (ushort*)carve((size_t)196608 * 2);
    if (off > ws_size) return;

    const int* srca = ei;
    const int* dsta = ei + NE;

    hipMemsetAsync(cnt, 0, (size_t)(2 * NN) * 4, stream);

    prep_fold<<<100, 256, 0, stream>>>(W_dst1, att_dst1, W_edge1, att_edge1,
                                       W_dst2, att_dst2, W_edge2, att_edge2,
                                       uf1, uf2, v1, v2);
    prep_wt<<<1536, 256, 0, stream>>>(W_src1, W_src2, Wf1, Wf2);
    hist_k<<<(NE + 255) / 256, 256, 0, stream>>>(dsta, cnt);
    csr_blocksum<<<NBLK, 256, 0, stream>>>(cnt, ntype, blks);
    csr_scanmid<<<1, 256, 0, stream>>>(blks, ntoff, gblk);
    csr_apply<<<NBLK, 256, 0, stream>>>(cnt, ntype, blks, ntoff, row_ptr,
                                        node_perm, inv_perm);
    scatter_k<<<(NE + 255) / 256, 256, 0, stream>>>(srca, dsta, etype, inv_perm,
                                                    row_ptr, cursor, spk, e2c);
    sedge_k<<<(NE + 255) / 256, 256, 0, stream>>>(eattr, etype, e2c, v1, v2,
                                                  sedge1c, sedge2c);

    // ---- layer 1 (fp32 input gathered+converted in-staging)
    gemm3_k<<<GGRID, 256, 0, stream>>>(nullptr, x, Wf1, uf1, att_src1,
                                       node_perm, ntoff, gblk, x_srcb, s_dst, s_src);
    attn_k<<<NN / 16, 256, 0, stream>>>(x_srcb, s_src, s_dst, sedge1c, row_ptr, spk,
                                        inv_perm, bias1, gamma1, beta1, hb, 1);

    // ---- layer 2 (bf16 permuted input, fully sequential staging)
    gemm3_k<<<GGRID, 256, 0, stream>>>(hb, nullptr, Wf2, uf2, att_src2,
                                       node_perm, ntoff, gblk, x_srcb, s_dst, s_src);
    attn_k<<<NN / 16, 256, 0, stream>>>(x_srcb, s_src, s_dst, sedge2c, row_ptr, spk,
                                        inv_perm, bias2, nullptr, nullptr, d_out, 2);
}

// Round 19
// 232.626 us; speedup vs baseline: 1.0787x; 1.0787x over previous
//
#include <hip/hip_runtime.h>

#define NN 50000
#define NE 400000
#define NH 4
#define NTY 3
#define ETY 4
#define EDIM 32
#define NBLK 196   // ceil(NN/256)
#define BM 32      // gemm rows per block
#define GGRID ((NN + BM - 1) / BM + NTY)   // flat gemm grid upper bound

typedef __attribute__((ext_vector_type(8))) short bf16x8;
typedef __attribute__((ext_vector_type(4))) float f32x4;

static __device__ __forceinline__ unsigned short f2bf(float f) {
    unsigned u = __float_as_uint(f);
    unsigned r = (u + 0x7FFFu + ((u >> 16) & 1u)) >> 16;   // RNE
    return (unsigned short)r;
}
static __device__ __forceinline__ float bf2f(unsigned short s) {
    return __uint_as_float(((unsigned)s) << 16);
}

// ---------------------------------------------------------------- prep: fold u(->Uf frag layout), v
__global__ __launch_bounds__(256) void prep_fold(
    const float* __restrict__ W_dst1, const float* __restrict__ att_dst1,
    const float* __restrict__ W_edge1, const float* __restrict__ att_edge1,
    const float* __restrict__ W_dst2, const float* __restrict__ att_dst2,
    const float* __restrict__ W_edge2, const float* __restrict__ att_edge2,
    ushort* __restrict__ uf1, ushort* __restrict__ uf2,
    float* __restrict__ v1, float* __restrict__ v2)
{
    int idx = blockIdx.x * 256 + threadIdx.x;   // 25600 total
    if (idx < 24576) {
        const float* W; const float* A; ushort* U; int i;
        if (idx < 12288) { W = W_dst1; A = att_dst1; U = uf1; i = idx; }
        else             { W = W_dst2; A = att_dst2; U = uf2; i = idx - 12288; }
        int d = i & 255, h = (i >> 8) & 3, t = (i >> 10) & 3, tn = i >> 12;
        const float* wp = W + tn * 65536 + d * 256 + h * 64;
        const float* ap = A + t * 256 + h * 64;
        float s = 0.f;
        #pragma unroll 8
        for (int c = 0; c < 64; ++c) s += wp[c] * ap[c];
        int th = t * 4 + h;
        int ks = d >> 5, g = (d >> 3) & 3, e = d & 7;
        U[(size_t)tn * 4096 + ks * 512 + (g * 16 + th) * 8 + e] = f2bf(s);
    } else {
        int i = idx - 24576;
        const float* W; const float* A; float* V;
        if (i < 512) { W = W_edge1; A = att_edge1; V = v1; }
        else         { W = W_edge2; A = att_edge2; V = v2; i -= 512; }
        int d = i & 31, h = (i >> 5) & 3, t = i >> 7;
        const float* wp = W + t * (EDIM * 256) + d * 256 + h * 64;
        const float* ap = A + t * 256 + h * 64;
        float s = 0.f;
        #pragma unroll 8
        for (int c = 0; c < 64; ++c) s += wp[c] * ap[c];
        V[(t * 4 + h) * 32 + d] = s;
    }
}

// ---------------------------------------------------------------- prep: Wf fragment layout
__global__ __launch_bounds__(256) void prep_wt(
    const float* __restrict__ W1, const float* __restrict__ W2,
    ushort* __restrict__ Wf1, ushort* __restrict__ Wf2)
{
    int idx = blockIdx.x * 256 + threadIdx.x;   // 393216 total
    const int HALF = 196608;
    const float* W = (idx < HALF) ? W1 : W2;
    ushort* O = (idx < HALF) ? Wf1 : Wf2;
    int i = (idx < HALF) ? idx : idx - HALF;
    int n = i & 255, k = (i >> 8) & 255, t = i >> 16;
    int c16 = n >> 4, r16 = n & 15;
    int ks = k >> 5, g = (k >> 3) & 3, e = k & 7;
    O[(size_t)t * 65536 + (c16 * 8 + ks) * 512 + (g * 16 + r16) * 8 + e] =
        f2bf(W[(size_t)t * 65536 + k * 256 + n]);
}

// ---------------------------------------------------------------- CSR build
__global__ void hist_k(const int* __restrict__ dst, int* __restrict__ cnt)
{
    int i = blockIdx.x * 256 + threadIdx.x;
    if (i < NE) atomicAdd(&cnt[dst[i]], 1);
}

__global__ __launch_bounds__(256) void csr_blocksum(
    const int* __restrict__ cnt, const int* __restrict__ ntype,
    int* __restrict__ blks)  // [4][NBLK]
{
    int tid = threadIdx.x, b = blockIdx.x;
    int j = b * 256 + tid;
    int c = (j < NN) ? cnt[j] : 0;
    int t = (j < NN) ? ntype[j] : 3;
    int p = (t < 3) ? (1 << (t * 10)) : 0;
    #pragma unroll
    for (int d = 1; d < 64; d <<= 1) { c += __shfl_xor(c, d); p += __shfl_xor(p, d); }
    __shared__ int ws[2][4];
    int lane = tid & 63, w = tid >> 6;
    if (lane == 0) { ws[0][w] = c; ws[1][w] = p; }
    __syncthreads();
    if (tid == 0) {
        int C = ws[0][0] + ws[0][1] + ws[0][2] + ws[0][3];
        int P = ws[1][0] + ws[1][1] + ws[1][2] + ws[1][3];
        blks[b]            = C;
        blks[NBLK + b]     = P & 1023;
        blks[2 * NBLK + b] = (P >> 10) & 1023;
        blks[3 * NBLK + b] = (P >> 20) & 1023;
    }
}

__global__ __launch_bounds__(256) void csr_scanmid(int* __restrict__ blks,
                                                   int* __restrict__ ntoff,
                                                   int* __restrict__ gblk)
{
    __shared__ int4 part[256];
    int tid = threadIdx.x;
    int4 v = make_int4(0, 0, 0, 0);
    if (tid < NBLK)
        v = make_int4(blks[tid], blks[NBLK + tid], blks[2 * NBLK + tid], blks[3 * NBLK + tid]);
    int4 orig = v;
    part[tid] = v;
    __syncthreads();
    for (int off = 1; off < 256; off <<= 1) {
        int4 u = (tid >= off) ? part[tid - off] : make_int4(0, 0, 0, 0);
        __syncthreads();
        part[tid].x += u.x; part[tid].y += u.y; part[tid].z += u.z; part[tid].w += u.w;
        __syncthreads();
    }
    int4 inc = part[tid];
    if (tid < NBLK) {
        blks[tid]            = inc.x - orig.x;
        blks[NBLK + tid]     = inc.y - orig.y;
        blks[2 * NBLK + tid] = inc.z - orig.z;
        blks[3 * NBLK + tid] = inc.w - orig.w;
    }
    if (tid == 255) {
        ntoff[0] = 0; ntoff[1] = inc.y; ntoff[2] = inc.y + inc.z;
        ntoff[3] = inc.y + inc.z + inc.w;
        int b0 = (inc.y + BM - 1) / BM;
        int b1 = (inc.z + BM - 1) / BM;
        int b2 = (inc.w + BM - 1) / BM;
        gblk[0] = 0; gblk[1] = b0; gblk[2] = b0 + b1; gblk[3] = b0 + b1 + b2;
    }
}

// Also emits inv_perm (original node -> permuted position).
__global__ __launch_bounds__(256) void csr_apply(
    const int* __restrict__ cnt, const int* __restrict__ ntype,
    const int* __restrict__ blks, const int* __restrict__ ntoff,
    int* __restrict__ row_ptr, int* __restrict__ node_perm,
    int* __restrict__ inv_perm)
{
    int tid = threadIdx.x, b = blockIdx.x;
    int j = b * 256 + tid;
    int c = (j < NN) ? cnt[j] : 0;
    int t = (j < NN) ? ntype[j] : 3;
    int p = (t < 3) ? (1 << (t * 10)) : 0;
    int lane = tid & 63, w = tid >> 6;
    int ic = c, ip = p;
    #pragma unroll
    for (int d = 1; d < 64; d <<= 1) {
        int uc = __shfl_up(ic, d), up = __shfl_up(ip, d);
        if (lane >= d) { ic += uc; ip += up; }
    }
    __shared__ int ws[2][4];
    if (lane == 63) { ws[0][w] = ic; ws[1][w] = ip; }
    __syncthreads();
    int coff = 0, poff = 0;
    for (int i = 0; i < w; ++i) { coff += ws[0][i]; poff += ws[1][i]; }
    int exc  = ic - c + coff;
    int expp = ip - p + poff;
    if (j < NN) {
        row_ptr[j] = blks[b] + exc;
        if (t < 3) {
            int tb   = blks[(t + 1) * NBLK + b];
            int tpfx = (expp >> (t * 10)) & 1023;
            int pos  = ntoff[t] + tb + tpfx;
            node_perm[pos] = j;
            inv_perm[j] = pos;
        }
    }
    if (j == 0) row_ptr[NN] = NE;
}

// Light scatter: CSR slot + packed (permuted src)|etype + edge->slot map.
__global__ void scatter_k(const int* __restrict__ src, const int* __restrict__ dst,
                          const int* __restrict__ etype, const int* __restrict__ inv,
                          const int* __restrict__ row_ptr, int* __restrict__ cursor,
                          int* __restrict__ spk, int* __restrict__ e2c)
{
    int i = blockIdx.x * 256 + threadIdx.x;
    if (i >= NE) return;
    int d = dst[i];
    int pos = row_ptr[d] + atomicAdd(&cursor[d], 1);
    spk[pos] = inv[src[i]] | (etype[i] << 16);
    e2c[i] = pos;
}

// Edge scores, edge order: eattr + e2c coalesced, v tables in LDS,
// results scatter-stored to CSR slots.
__global__ __launch_bounds__(256) void sedge_k(
    const float* __restrict__ eattr, const int* __restrict__ etype,
    const int* __restrict__ e2c,
    const float* __restrict__ v1, const float* __restrict__ v2,
    float* __restrict__ sedge1c, float* __restrict__ sedge2c)
{
    __shared__ float v1l[512], v2l[512];
    int tid = threadIdx.x;
    v1l[tid] = v1[tid]; v1l[tid + 256] = v1[tid + 256];
    v2l[tid] = v2[tid]; v2l[tid + 256] = v2[tid + 256];
    __syncthreads();

    int i = blockIdx.x * 256 + tid;
    if (i >= NE) return;
    int t = etype[i];
    int pos = e2c[i];
    float4 ea[8];
    #pragma unroll
    for (int q = 0; q < 8; ++q) ea[q] = *(const float4*)(eattr + (size_t)i * 32 + q * 4);
    float4 o1, o2;
    #pragma unroll
    for (int h = 0; h < 4; ++h) {
        const float* vp1 = v1l + (t * 4 + h) * 32;
        const float* vp2 = v2l + (t * 4 + h) * 32;
        float s1 = 0.f, s2 = 0.f;
        #pragma unroll
        for (int q = 0; q < 8; ++q) {
            float4 w1 = *(const float4*)(vp1 + q * 4);
            float4 w2 = *(const float4*)(vp2 + q * 4);
            s1 += ea[q].x * w1.x + ea[q].y * w1.y + ea[q].z * w1.z + ea[q].w * w1.w;
            s2 += ea[q].x * w2.x + ea[q].y * w2.y + ea[q].z * w2.z + ea[q].w * w2.w;
        }
        ((float*)&o1)[h] = s1;
        ((float*)&o2)[h] = s2;
    }
    *(float4*)(sedge1c + (size_t)pos * 4) = o1;
    *(float4*)(sedge2c + (size_t)pos * 4) = o2;
}

// ---------------------------------------------------------------- fused GEMM + s_dst + s_src (+convert)
// Activations in PERMUTED order: xout/s_src written at rp (contiguous);
// layer-2 input read at rp (sequential). Layer-1 gathers x via node_perm.
__global__ __launch_bounds__(256) void gemm3_k(
    const ushort* __restrict__ xb, const float* __restrict__ xf,
    const ushort* __restrict__ Wf, const ushort* __restrict__ Uf,
    const float* __restrict__ att_src,
    const int* __restrict__ node_perm, const int* __restrict__ ntoff,
    const int* __restrict__ gblk,
    ushort* __restrict__ xout, float* __restrict__ s_dst,
    float* __restrict__ s_src)
{
    int b = blockIdx.x;
    if (b >= gblk[3]) return;
    int t = (b >= gblk[1]) + (b >= gblk[2]);
    int row0 = ntoff[t] + (b - gblk[t]) * BM;
    int seg1 = ntoff[t + 1];

    __shared__ __align__(16) ushort Xl[BM * 256];  // 16 KB

    int tid = threadIdx.x;
    int w = tid >> 6, l = tid & 63;
    int kb = (tid & 31) * 16;               // bf16 byte offset in a 512B row

    #pragma unroll
    for (int it = 0; it < 4; ++it) {
        int row = it * 8 + (tid >> 5);      // 8 rows per iteration
        int rp = row0 + row;
        int rr = (rp < seg1) ? rp : seg1 - 1;
        uint4 pv;
        if (xf) {
            int gr = node_perm[rr];
            const char* src = (const char*)(xf + (size_t)gr * 256) + kb * 2;
            float4 f0 = *(const float4*)(src);
            float4 f1 = *(const float4*)(src + 16);
            pv.x = (unsigned)f2bf(f0.x) | ((unsigned)f2bf(f0.y) << 16);
            pv.y = (unsigned)f2bf(f0.z) | ((unsigned)f2bf(f0.w) << 16);
            pv.z = (unsigned)f2bf(f1.x) | ((unsigned)f2bf(f1.y) << 16);
            pv.w = (unsigned)f2bf(f1.z) | ((unsigned)f2bf(f1.w) << 16);
        } else {
            pv = *(const uint4*)((const char*)(xb + (size_t)rr * 256) + kb);
        }
        *(uint4*)((char*)Xl + row * 512 + (kb ^ ((row & 7) << 4))) = pv;
    }
    __syncthreads();

    int g = l >> 4, r16 = l & 15;
    const ushort* wfb = Wf + (size_t)(t * 16 + w * 4) * 8 * 512;  // this wave's 4 c16-tiles
    const ushort* ufb = Uf + (size_t)t * 4096;

    f32x4 acc[2][4];                         // [fr (x-row group)][cf (col group)]
    #pragma unroll
    for (int i = 0; i < 2; ++i)
        #pragma unroll
        for (int j = 0; j < 4; ++j) acc[i][j] = (f32x4){0.f, 0.f, 0.f, 0.f};
    f32x4 uacc[2] = {{0.f,0.f,0.f,0.f},{0.f,0.f,0.f,0.f}};

    // register double-buffer for W/U fragments
    bf16x8 aW[4], aU, nW[4], nU;
    #pragma unroll
    for (int cf = 0; cf < 4; ++cf)
        aW[cf] = *(const bf16x8*)(wfb + (cf * 8 + 0) * 512 + l * 8);
    aU = *(const bf16x8*)(ufb + 0 * 512 + l * 8);

    #pragma unroll
    for (int ks = 0; ks < 8; ++ks) {
        if (ks < 7) {
            #pragma unroll
            for (int cf = 0; cf < 4; ++cf)
                nW[cf] = *(const bf16x8*)(wfb + (cf * 8 + ks + 1) * 512 + l * 8);
            nU = *(const bf16x8*)(ufb + (ks + 1) * 512 + l * 8);
        }
        int kbyte = ks * 64 + g * 16;
        bf16x8 b0 = *(const bf16x8*)((const char*)Xl + r16 * 512 + (kbyte ^ ((r16 & 7) << 4)));
        bf16x8 b1 = *(const bf16x8*)((const char*)Xl + (16 + r16) * 512 + (kbyte ^ (((16 + r16) & 7) << 4)));
        #pragma unroll
        for (int cf = 0; cf < 4; ++cf) {
            acc[0][cf] = __builtin_amdgcn_mfma_f32_16x16x32_bf16(aW[cf], b0, acc[0][cf], 0, 0, 0);
            acc[1][cf] = __builtin_amdgcn_mfma_f32_16x16x32_bf16(aW[cf], b1, acc[1][cf], 0, 0, 0);
        }
        uacc[0] = __builtin_amdgcn_mfma_f32_16x16x32_bf16(aU, b0, uacc[0], 0, 0, 0);
        uacc[1] = __builtin_amdgcn_mfma_f32_16x16x32_bf16(aU, b1, uacc[1], 0, 0, 0);
        if (ks < 7) {
            #pragma unroll
            for (int cf = 0; cf < 4; ++cf) aW[cf] = nW[cf];
            aU = nU;
        }
    }

    // s_src epilogue: head w, s_src[rp, te*4+w] = sum_c acc(row, c) * att_src[te][w][c]
    float p[4][2];
    #pragma unroll
    for (int te = 0; te < 4; ++te) { p[te][0] = 0.f; p[te][1] = 0.f; }
    #pragma unroll
    for (int te = 0; te < 4; ++te) {
        #pragma unroll
        for (int cf = 0; cf < 4; ++cf) {
            float4 av = *(const float4*)(att_src + te * 256 + w * 64 + cf * 16 + g * 4);
            #pragma unroll
            for (int fr = 0; fr < 2; ++fr) {
                p[te][fr] += acc[fr][cf][0] * av.x + acc[fr][cf][1] * av.y
                           + acc[fr][cf][2] * av.z + acc[fr][cf][3] * av.w;
            }
        }
    }
    #pragma unroll
    for (int te = 0; te < 4; ++te)
        #pragma unroll
        for (int fr = 0; fr < 2; ++fr) {
            p[te][fr] += __shfl_xor(p[te][fr], 16);
            p[te][fr] += __shfl_xor(p[te][fr], 32);
        }

    int col0 = w * 64;
    #pragma unroll
    for (int fr = 0; fr < 2; ++fr) {
        int rp = row0 + fr * 16 + r16;       // D col = lane&15 -> X row
        if (rp < seg1) {
            ushort* orow = xout + (size_t)rp * 256;
            #pragma unroll
            for (int cf = 0; cf < 4; ++cf) {
                ushort4 o;
                o.x = f2bf(acc[fr][cf][0]); o.y = f2bf(acc[fr][cf][1]);
                o.z = f2bf(acc[fr][cf][2]); o.w = f2bf(acc[fr][cf][3]);
                *(ushort4*)(orow + col0 + cf * 16 + g * 4) = o;   // D row m -> channel
            }
            if (w == 0) {
                int gr = node_perm[rp];
                *(float4*)(s_dst + (size_t)gr * 16 + g * 4) =
                    make_float4(uacc[fr][0], uacc[fr][1], uacc[fr][2], uacc[fr][3]);
            }
            if (g == 0) {
                #pragma unroll
                for (int te = 0; te < 4; ++te)
                    s_src[(size_t)rp * 16 + te * 4 + w] = p[te][fr];
            }
        }
    }
}

// ---------------------------------------------------------------- fused attention
static __device__ __forceinline__ float4 alpha_slot(
    int k, int n, const int* __restrict__ spk, const float* __restrict__ s_src,
    const float* __restrict__ s_dst, const float* __restrict__ sedgec, int* sOut)
{
    int pk = spk[k];
    int s = pk & 0xFFFF;      // permuted src position
    int t = pk >> 16;
    float4 ss = *(const float4*)(s_src + (size_t)s * 16 + t * 4);
    float4 sd = *(const float4*)(s_dst + (size_t)n * 16 + t * 4);
    float4 se = *(const float4*)(sedgec + (size_t)k * 4);
    float4 a;
    a.x = ss.x + sd.x + se.x; a.x = (a.x >= 0.f) ? a.x : 0.2f * a.x;
    a.y = ss.y + sd.y + se.y; a.y = (a.y >= 0.f) ? a.y : 0.2f * a.y;
    a.z = ss.z + sd.z + se.z; a.z = (a.z >= 0.f) ? a.z : 0.2f * a.z;
    a.w = ss.w + sd.w + se.w; a.w = (a.w >= 0.f) ? a.w : 0.2f * a.w;
    *sOut = s;
    return a;
}

// Block = 16 nodes. Phase A: 16-lane group per node; zero-padded slot tables.
// Phase B: fixed-step unrolled gather (8 loads in flight). Mode-1 output goes
// to PERMUTED position inv[n] (layer-2 gemm reads it sequentially).
__global__ __launch_bounds__(256) void attn_k(
    const ushort* __restrict__ xsb, const float* __restrict__ s_src,
    const float* __restrict__ s_dst, const float* __restrict__ sedgec,
    const int* __restrict__ row_ptr, const int* __restrict__ spk,
    const int* __restrict__ inv,
    const float* __restrict__ bias, const float* __restrict__ gamma,
    const float* __restrict__ beta, void* __restrict__ out, int mode)
{
    __shared__ float  wlds[16][256];   // 16 KB
    __shared__ int    slds[16][64];    //  4 KB
    __shared__ float4 mxl[16], invl[16];

    int w = threadIdx.x >> 6;
    int lane = threadIdx.x & 63;
    int j = lane >> 4, li = lane & 15;
    int nid = w * 4 + j;
    int n = blockIdx.x * 16 + nid;
    int beg = row_ptr[n], end = row_ptr[n + 1];
    int deg = end - beg;

    // ---- phase A: weights (16 lanes per node)
    int k0 = beg + li;
    bool act = li < deg;
    int sF = 0;
    float4 aF = make_float4(-1e30f, -1e30f, -1e30f, -1e30f);
    if (act) aF = alpha_slot(k0, n, spk, s_src, s_dst, sedgec, &sF);

    float4 mx = aF;
    for (int k = k0 + 16; k < end; k += 16) {   // deg > 16: ~0.3% of nodes
        int s2; float4 t = alpha_slot(k, n, spk, s_src, s_dst, sedgec, &s2);
        mx.x = fmaxf(mx.x, t.x); mx.y = fmaxf(mx.y, t.y);
        mx.z = fmaxf(mx.z, t.z); mx.w = fmaxf(mx.w, t.w);
    }
    #pragma unroll
    for (int d = 1; d < 16; d <<= 1) {
        mx.x = fmaxf(mx.x, __shfl_xor(mx.x, d, 16));
        mx.y = fmaxf(mx.y, __shfl_xor(mx.y, d, 16));
        mx.z = fmaxf(mx.z, __shfl_xor(mx.z, d, 16));
        mx.w = fmaxf(mx.w, __shfl_xor(mx.w, d, 16));
    }
    float4 ex = make_float4(0.f, 0.f, 0.f, 0.f);
    if (act) {
        ex.x = __expf(aF.x - mx.x); ex.y = __expf(aF.y - mx.y);
        ex.z = __expf(aF.z - mx.z); ex.w = __expf(aF.w - mx.w);
    }
    float4 sm = ex;
    for (int k = k0 + 16; k < end; k += 16) {
        int s2; float4 t = alpha_slot(k, n, spk, s_src, s_dst, sedgec, &s2);
        sm.x += __expf(t.x - mx.x); sm.y += __expf(t.y - mx.y);
        sm.z += __expf(t.z - mx.z); sm.w += __expf(t.w - mx.w);
    }
    #pragma unroll
    for (int d = 1; d < 16; d <<= 1) {
        sm.x += __shfl_xor(sm.x, d, 16); sm.y += __shfl_xor(sm.y, d, 16);
        sm.z += __shfl_xor(sm.z, d, 16); sm.w += __shfl_xor(sm.w, d, 16);
    }
    float4 inv4;
    inv4.x = 1.f / (sm.x + 1e-16f); inv4.y = 1.f / (sm.y + 1e-16f);
    inv4.z = 1.f / (sm.z + 1e-16f); inv4.w = 1.f / (sm.w + 1e-16f);

    if (act) {
        *(float4*)&wlds[nid][li * 4] = make_float4(ex.x * inv4.x, ex.y * inv4.y,
                                                   ex.z * inv4.z, ex.w * inv4.w);
        slds[nid][li] = sF;
    }
    for (int k = k0 + 16; k < end && (k - beg) < 64; k += 16) {  // slots 16..63
        int s2; float4 t = alpha_slot(k, n, spk, s_src, s_dst, sedgec, &s2);
        int slot = k - beg;
        *(float4*)&wlds[nid][slot * 4] = make_float4(
            __expf(t.x - mx.x) * inv4.x, __expf(t.y - mx.y) * inv4.y,
            __expf(t.z - mx.z) * inv4.z, __expf(t.w - mx.w) * inv4.w);
        slds[nid][slot] = s2;
    }
    // zero-pad slots deg..round8(deg)-1: zero weight * row 0 contributes nothing
    {
        int nf = (deg < 64) ? deg : 64;
        int pad = ((nf + 7) & ~7) - nf;
        if (li < pad) {
            *(float4*)&wlds[nid][(nf + li) * 4] = make_float4(0.f, 0.f, 0.f, 0.f);
            slds[nid][nf + li] = 0;
        }
    }
    if (li == 0) { mxl[nid] = mx; invl[nid] = inv4; }

    // ---- phase B: wave processes its 4 nodes (wave-private LDS, no barrier)
    int h2 = lane >> 4;
    for (int jj = 0; jj < 4; ++jj) {
        int nb = w * 4 + jj;
        int nn = blockIdx.x * 16 + nb;
        int begj = __shfl(beg, jj * 16);
        int degj = __shfl(deg, jj * 16);

        float4 acc = make_float4(0.f, 0.f, 0.f, 0.f);
        int nfast = (degj < 64) ? degj : 64;
        int nR = (nfast + 7) & ~7;
        for (int i = 0; i < nR; i += 8) {
            #pragma unroll
            for (int u = 0; u < 8; ++u) {
                float wv = wlds[nb][(i + u) * 4 + h2];
                int s = slds[nb][i + u];
                ushort4 xv = *(const ushort4*)(xsb + (size_t)s * 256 + lane * 4);
                acc.x += wv * bf2f(xv.x);
                acc.y += wv * bf2f(xv.y);
                acc.z += wv * bf2f(xv.z);
                acc.w += wv * bf2f(xv.w);
            }
        }
        if (degj > 64) {                        // vanishingly rare
            float4 mxj = mxl[nb], invj = invl[nb];
            float mxh  = (h2 == 0) ? mxj.x  : (h2 == 1) ? mxj.y  : (h2 == 2) ? mxj.z  : mxj.w;
            float invh = (h2 == 0) ? invj.x : (h2 == 1) ? invj.y : (h2 == 2) ? invj.z : invj.w;
            for (int k = begj + 64; k < begj + degj; ++k) {
                int pk = spk[k];
                int s = pk & 0xFFFF, t = pk >> 16;
                float a = s_src[(size_t)s * 16 + t * 4 + h2]
                        + s_dst[(size_t)nn * 16 + t * 4 + h2]
                        + sedgec[(size_t)k * 4 + h2];
                a = (a >= 0.f) ? a : 0.2f * a;
                float wv = __expf(a - mxh) * invh;
                ushort4 xv = *(const ushort4*)(xsb + (size_t)s * 256 + lane * 4);
                acc.x += wv * bf2f(xv.x);
                acc.y += wv * bf2f(xv.y);
                acc.z += wv * bf2f(xv.z);
                acc.w += wv * bf2f(xv.w);
            }
        }

        if (mode == 1) {
            float4 bb = *(const float4*)(bias + lane * 4);
            float vals[4] = { acc.x + bb.x, acc.y + bb.y, acc.z + bb.z, acc.w + bb.w };
            float s = vals[0] + vals[1] + vals[2] + vals[3];
            s += __shfl_xor(s, 1); s += __shfl_xor(s, 2); s += __shfl_xor(s, 4);
            s += __shfl_xor(s, 8); s += __shfl_xor(s, 16); s += __shfl_xor(s, 32);
            float mu = s * (1.f / 256.f);
            float q = 0.f;
            #pragma unroll
            for (int jq = 0; jq < 4; ++jq) { float d = vals[jq] - mu; q += d * d; }
            q += __shfl_xor(q, 1); q += __shfl_xor(q, 2); q += __shfl_xor(q, 4);
            q += __shfl_xor(q, 8); q += __shfl_xor(q, 16); q += __shfl_xor(q, 32);
            float r = rsqrtf(q * (1.f / 256.f) + 1e-5f);
            float4 gg = *(const float4*)(gamma + lane * 4);
            float4 be = *(const float4*)(beta + lane * 4);
            ushort4 o; float y;
            y = (vals[0] - mu) * r * gg.x + be.x; o.x = f2bf((y > 0.f) ? y : (__expf(y) - 1.f));
            y = (vals[1] - mu) * r * gg.y + be.y; o.y = f2bf((y > 0.f) ? y : (__expf(y) - 1.f));
            y = (vals[2] - mu) * r * gg.z + be.z; o.z = f2bf((y > 0.f) ? y : (__expf(y) - 1.f));
            y = (vals[3] - mu) * r * gg.w + be.w; o.w = f2bf((y > 0.f) ? y : (__expf(y) - 1.f));
            int npos = inv[nn];
            *(ushort4*)((ushort*)out + (size_t)npos * 256 + lane * 4) = o;
        } else {
            float4 am = acc;
            am.x += __shfl_xor(am.x, 16); am.x += __shfl_xor(am.x, 32);
            am.y += __shfl_xor(am.y, 16); am.y += __shfl_xor(am.y, 32);
            am.z += __shfl_xor(am.z, 16); am.z += __shfl_xor(am.z, 32);
            am.w += __shfl_xor(am.w, 16); am.w += __shfl_xor(am.w, 32);
            if (lane < 16) {
                float4 bb = *(const float4*)(bias + lane * 4);
                float4 o;
                o.x = am.x * 0.25f + bb.x;
                o.y = am.y * 0.25f + bb.y;
                o.z = am.z * 0.25f + bb.z;
                o.w = am.w * 0.25f + bb.w;
                *(float4*)((float*)out + (size_t)nn * 64 + lane * 4) = o;
            }
        }
    }
}

// ---------------------------------------------------------------- launch
extern "C" void kernel_launch(void* const* d_in, const int* in_sizes, int n_in,
                              void* d_out, int out_size, void* d_ws, size_t ws_size,
                              hipStream_t stream)
{
    (void)in_sizes; (void)n_in; (void)out_size;
    const float* x        = (const float*)d_in[0];
    const int*   ei       = (const int*)d_in[1];
    const int*   ntype    = (const int*)d_in[2];
    const int*   etype    = (const int*)d_in[3];
    const float* eattr    = (const float*)d_in[4];
    const float* W_src1   = (const float*)d_in[5];
    const float* W_dst1   = (const float*)d_in[6];
    const float* att_src1 = (const float*)d_in[7];
    const float* att_dst1 = (const float*)d_in[8];
    const float* W_edge1  = (const float*)d_in[9];
    const float* att_edge1= (const float*)d_in[10];
    const float* bias1    = (const float*)d_in[11];
    const float* gamma1   = (const float*)d_in[12];
    const float* beta1    = (const float*)d_in[13];
    const float* W_src2   = (const float*)d_in[14];
    const float* W_dst2   = (const float*)d_in[15];
    const float* att_src2 = (const float*)d_in[16];
    const float* att_dst2 = (const float*)d_in[17];
    const float* W_edge2  = (const float*)d_in[18];
    const float* att_edge2= (const float*)d_in[19];
    const float* bias2    = (const float*)d_in[20];

    char* w = (char*)d_ws;
    size_t off = 0;
    auto carve = [&](size_t bytes) -> char* {
        char* p = w + off;
        off = (off + bytes + 255) & ~(size_t)255;
        return p;
    };
    ushort* x_srcb  = (ushort*)carve((size_t)NN * 256 * 2);   // bf16 x_src (permuted)
    ushort* hb      = (ushort*)carve((size_t)NN * 256 * 2);   // bf16 h (permuted)
    float* s_src    = (float*)carve((size_t)NN * 16 * 4);     // permuted
    float* s_dst    = (float*)carve((size_t)NN * 16 * 4);     // original
    float* sedge1c  = (float*)carve((size_t)NE * 4 * 4);
    float* sedge2c  = (float*)carve((size_t)NE * 4 * 4);
    int*   cnt      = (int*)carve((size_t)(2 * NN) * 4);
    int*   cursor   = cnt + NN;
    int*   row_ptr  = (int*)carve((size_t)(NN + 1) * 4);
    int*   spk      = (int*)carve((size_t)NE * 4);
    int*   e2c      = (int*)carve((size_t)NE * 4);
    int*   node_perm= (int*)carve((size_t)NN * 4);
    int*   inv_perm = (int*)carve((size_t)NN * 4);
    int*   ntoff    = (int*)carve(4 * 4);
    int*   gblk     = (int*)carve(4 * 4);
    int*   blks     = (int*)carve((size_t)(4 * NBLK) * 4);
    ushort* uf1     = (ushort*)carve(12288 * 2);
    ushort* uf2     = (ushort*)carve(12288 * 2);
    float* v1       = (float*)carve(512 * 4);
    float* v2       = (float*)carve(512 * 4);
    ushort* Wf1     = (ushort*)carve((size_t)196608 * 2);
    ushort* Wf2     = (ushort*)carve((size_t)196608 * 2);
    if (off > ws_size) return;

    const int* srca = ei;
    const int* dsta = ei + NE;

    hipMemsetAsync(cnt, 0, (size_t)(2 * NN) * 4, stream);

    prep_fold<<<100, 256, 0, stream>>>(W_dst1, att_dst1, W_edge1, att_edge1,
                                       W_dst2, att_dst2, W_edge2, att_edge2,
                                       uf1, uf2, v1, v2);
    prep_wt<<<1536, 256, 0, stream>>>(W_src1, W_src2, Wf1, Wf2);
    hist_k<<<(NE + 255) / 256, 256, 0, stream>>>(dsta, cnt);
    csr_blocksum<<<NBLK, 256, 0, stream>>>(cnt, ntype, blks);
    csr_scanmid<<<1, 256, 0, stream>>>(blks, ntoff, gblk);
    csr_apply<<<NBLK, 256, 0, stream>>>(cnt, ntype, blks, ntoff, row_ptr,
                                        node_perm, inv_perm);
    scatter_k<<<(NE + 255) / 256, 256, 0, stream>>>(srca, dsta, etype, inv_perm,
                                                    row_ptr, cursor, spk, e2c);
    sedge_k<<<(NE + 255) / 256, 256, 0, stream>>>(eattr, etype, e2c, v1, v2,
                                                  sedge1c, sedge2c);

    // ---- layer 1 (fp32 input gathered+converted in-staging)
    gemm3_k<<<GGRID, 256, 0, stream>>>(nullptr, x, Wf1, uf1, att_src1,
                                       node_perm, ntoff, gblk, x_srcb, s_dst, s_src);
    attn_k<<<NN / 16, 256, 0, stream>>>(x_srcb, s_src, s_dst, sedge1c, row_ptr, spk,
                                        inv_perm, bias1, gamma1, beta1, hb, 1);

    // ---- layer 2 (bf16 permuted input, fully sequential staging)
    gemm3_k<<<GGRID, 256, 0, stream>>>(hb, nullptr, Wf2, uf2, att_src2,
                                       node_perm, ntoff, gblk, x_srcb, s_dst, s_src);
    attn_k<<<NN / 16, 256, 0, stream>>>(x_srcb, s_src, s_dst, sedge2c, row_ptr, spk,
                                        inv_perm, bias2, nullptr, nullptr, d_out, 2);
}